// Round 6
// baseline (668.868 us; speedup 1.0000x reference)
//
#include <hip/hip_runtime.h>

// Problem constants (from reference setup)
#define NB 128            // batches
#define NA 29             // atoms per batch
#define BN (NB*NA)        // 3712 nodes
#define FD 64             // feature dim
#define RPLANE (BN*64*28) // one iteration's edge projections: 6,651,904 floats

// ws layout (floats): logc[64] | rp[RPLANE] | x[BN*512]   (~34.2 MB)

// ---------------------------------------------------------------------------
// Kernel 0: 64 binomial log-coefficients (was 3 lgammaf calls per thread in
// the edge kernel = ~30% of its instruction count).
// ---------------------------------------------------------------------------
__global__ void init_logc_kernel(float* __restrict__ logc)
{
  const int k = threadIdx.x;   // 64 threads
  logc[k] = lgammaf(64.0f) - lgammaf((float)k + 1.0f) - lgammaf(64.0f - (float)k);
}

// ---------------------------------------------------------------------------
// Kernel A: one block per (batch,dst) node; 28 edges; radial basis projected
// through ONE iteration's mp_basis_w slice. Writes rp[(bn*64+g)*28 + jr].
// Also zeroes d_out when outz != null (stream-ordered before iter1 atomics;
// re-zeroed every call since the harness does not re-poison between replays).
// ---------------------------------------------------------------------------
__global__ __launch_bounds__(256, 3) void edge_rproj_kernel(
    const float* __restrict__ pos,      // [BN][3]
    const float* __restrict__ Wb,       // [64][64] (iteration slice)
    const float* __restrict__ logc_tab, // [64]
    float* __restrict__ rp,
    float* __restrict__ outz)
{
  __shared__ float elu[28], el1mu[28], efc[28];
  __shared__ float rads[28][FD];
  const int bn = blockIdx.x, b = bn / NA, n = bn - b*NA;
  const int tid = threadIdx.x, lane = tid & 63, wv = tid >> 6;

  if (outz != nullptr && bn == 0 && tid < NB) outz[tid] = 0.0f;

  if (tid < 28) {
    const int jr = tid, j = jr + (jr >= n ? 1 : 0);
    const float dx = pos[(b*NA+j)*3+0] - pos[(b*NA+n)*3+0];
    const float dy = pos[(b*NA+j)*3+1] - pos[(b*NA+n)*3+1];
    const float dz = pos[(b*NA+j)*3+2] - pos[(b*NA+n)*3+2];
    const float r  = sqrtf(dx*dx + dy*dy + dz*dz + 1e-12f);
    const float u  = 1.0f/(1.0f + r);
    elu[jr]   = logf(u);
    el1mu[jr] = logf(fmaxf(1.0f - u, 1e-12f));
    const float x2 = (r*0.2f)*(r*0.2f);
    efc[jr] = (x2 < 1.0f) ? expf(1.0f - 1.0f/fmaxf(1.0f - x2, 1e-12f)) : 0.0f;
  }
  const float kk   = (float)lane;
  const float logc = logc_tab[lane];
  __syncthreads();                      // elu/el1mu/efc shared across waves

  #pragma unroll
  for (int i = 0; i < 7; ++i) {         // wave-private rows: no barrier below
    const int e = wv*7 + i;
    rads[e][lane] = expf(logc + kk*elu[e] + (63.0f - kk)*el1mu[e]) * efc[e];
  }
  float wb[64];
  #pragma unroll
  for (int k = 0; k < 64; ++k) wb[k] = Wb[k*FD + lane];

  #pragma unroll
  for (int i = 0; i < 7; ++i) {
    const int jr = wv*7 + i;
    float a0 = 0.0f;
    #pragma unroll
    for (int k4 = 0; k4 < 16; ++k4) {
      const float4 rv = *(const float4*)&rads[jr][k4*4];  // same-wave RAW
      a0 += wb[k4*4+0]*rv.x + wb[k4*4+1]*rv.y + wb[k4*4+2]*rv.z + wb[k4*4+3]*rv.w;
    }
    rp[((size_t)bn*64 + lane)*28 + jr] = a0;
  }
}

// ---------------------------------------------------------------------------
// 20-path Clebsch-Gordan tensor product at one feature index.
// ---------------------------------------------------------------------------
__device__ __forceinline__ void tp20(const float* a, const float* bb,
                                     const float* w, float* o)
{
  #pragma unroll
  for (int p1 = 0; p1 < 2; ++p1) {
    #pragma unroll
    for (int p2 = 0; p2 < 2; ++p2) {
      const float* w5 = w + 5*(2*p1 + p2);
      const float s1 = a[p1*4+0], x1 = a[p1*4+1], y1 = a[p1*4+2], z1 = a[p1*4+3];
      const float s2 = bb[p2*4+0], x2 = bb[p2*4+1], y2 = bb[p2*4+2], z2 = bb[p2*4+3];
      const int so = (p1 == p2) ? 0 : 4;   // dest parity for T1..T4
      const int vo = 4 - so;               // dest parity for T5 (cross)
      o[so+0] += w5[0]*(s1*s2) + w5[3]*(x1*x2 + y1*y2 + z1*z2);
      o[so+1] += w5[1]*(s1*x2) + w5[2]*(x1*s2);
      o[so+2] += w5[1]*(s1*y2) + w5[2]*(y1*s2);
      o[so+3] += w5[1]*(s1*z2) + w5[2]*(z1*s2);
      o[vo+1] += w5[4]*(y1*z2 - z1*y2);
      o[vo+2] += w5[4]*(z1*x2 - x1*z2);
      o[vo+3] += w5[4]*(x1*y2 - y1*x2);
    }
  }
}

// ---------------------------------------------------------------------------
// Per-node dense (one node per WAVE): input row in the wave's private LDS row
// (broadcast float4 reads); weights f-outer coalesced scalar loads from the
// ORIGINAL [p][sel][f][g] layout (L2-hot, 256 B/wave-instruction).
// ---------------------------------------------------------------------------
__device__ __forceinline__ void denseRow(const float* __restrict__ in,
                                         const float* __restrict__ W,
                                         const float* __restrict__ bias,
                                         int g, float o[8])
{
  #pragma unroll
  for (int p = 0; p < 2; ++p) {
    {
      const float* Wp = W + (p*2+0)*4096 + g;
      float acc = bias ? bias[p*64 + g] : 0.0f;
      #pragma unroll
      for (int f4 = 0; f4 < 16; ++f4) {
        const float w0 = Wp[(f4*4+0)*64], w1 = Wp[(f4*4+1)*64];
        const float w2 = Wp[(f4*4+2)*64], w3 = Wp[(f4*4+3)*64];
        const float4 xv = *(const float4*)&in[(p*4+0)*64 + f4*4];
        acc += w0*xv.x + w1*xv.y + w2*xv.z + w3*xv.w;
      }
      o[p*4+0] = acc;
    }
    {
      const float* Wp = W + (p*2+1)*4096 + g;
      float a1 = 0.0f, a2 = 0.0f, a3 = 0.0f;
      #pragma unroll
      for (int f4 = 0; f4 < 16; ++f4) {
        const float w0 = Wp[(f4*4+0)*64], w1 = Wp[(f4*4+1)*64];
        const float w2 = Wp[(f4*4+2)*64], w3 = Wp[(f4*4+3)*64];
        const float4 xa = *(const float4*)&in[(p*4+1)*64 + f4*4];
        const float4 xb = *(const float4*)&in[(p*4+2)*64 + f4*4];
        const float4 xc = *(const float4*)&in[(p*4+3)*64 + f4*4];
        a1 += w0*xa.x + w1*xa.y + w2*xa.z + w3*xa.w;
        a2 += w0*xb.x + w1*xb.y + w2*xb.z + w3*xb.w;
        a3 += w0*xc.x + w1*xc.y + w2*xc.z + w3*xc.w;
      }
      o[p*4+1] = a1; o[p*4+2] = a2; o[p*4+3] = a3;
    }
  }
}

// ---------------------------------------------------------------------------
// Kernel B/C: one full iteration (messages + all per-node phases) fused.
// Block = (batch, shard of 8 nodes), 512 threads = 8 waves; wave r owns node
// n = shard*8 + r, lane g owns feature g. y never leaves registers.
// __launch_bounds__(512, 2): 2 blocks/CU -> 16 waves/CU -> 4 waves/SIMD,
// VGPR cap 128 (round-5's node kernel hit 200 VGPR -> 2 waves/SIMD -> 9%
// occupancy; the cap buys occupancy, spill tripwire = WRITE_SIZE).
// ---------------------------------------------------------------------------
template<bool LAST>
__global__ __launch_bounds__(512, 2) void iter_kernel(
    const int*   __restrict__ Z,
    const float* __restrict__ pos,
    const float* __restrict__ Ef,
    const float* __restrict__ embed,
    const float* __restrict__ wtp,      // mp_tp_w slice [20][64]
    const float* __restrict__ d1w, const float* __restrict__ d1b,
    const float* __restrict__ d2w, const float* __restrict__ d2b,
    const float* __restrict__ tens_w,
    const float* __restrict__ tdw,
    const float* __restrict__ td_tp_w,
    const float* __restrict__ out_w,
    const float* __restrict__ ebias,
    const float* __restrict__ rp,
    const float* __restrict__ xin,      // LAST only
    float* __restrict__ xout,           // !LAST only
    float* __restrict__ out)            // LAST only
{
  __shared__ float x_sh[NA][8][FD];     // LAST: full x; !LAST: only [.][0][.] (embeddings)
  __shared__ float posb[NA][3];
  __shared__ float us_sh[8][28][3];
  __shared__ float row[8][8][FD];       // wave-private dense staging rows

  const int bi = blockIdx.x, b = bi >> 2, shard = bi & 3;
  const int tid = threadIdx.x, r = tid >> 6, g = tid & 63;

  if (tid < NA) {
    posb[tid][0] = pos[(b*NA+tid)*3+0];
    posb[tid][1] = pos[(b*NA+tid)*3+1];
    posb[tid][2] = pos[(b*NA+tid)*3+2];
  }
  __syncthreads();

  if constexpr (!LAST) {
    for (int idx = tid; idx < NA*FD; idx += 512)
      x_sh[idx>>6][0][idx&63] = embed[Z[b*NA + (idx>>6)]*FD + (idx&63)];
  } else {
    float4* dst = (float4*)&x_sh[0][0][0];
    const float4* src = (const float4*)(xin + (size_t)b*NA*512);
    for (int i = tid; i < NA*512/4; i += 512) dst[i] = src[i];
  }
  if (tid < 224) {
    const int rr = tid/28, jr = tid - rr*28, nn = shard*8 + rr;
    if (nn < NA) {
      const int j = jr + (jr >= nn ? 1 : 0);
      const float dx = posb[j][0]-posb[nn][0];
      const float dy = posb[j][1]-posb[nn][1];
      const float dz = posb[j][2]-posb[nn][2];
      const float ri = 1.0f / sqrtf(dx*dx + dy*dy + dz*dz + 1e-12f);
      us_sh[rr][jr][0] = dx*ri; us_sh[rr][jr][1] = dy*ri; us_sh[rr][jr][2] = dz*ri;
    }
  }
  __syncthreads();                       // everything below is wave-private

  const int n = shard*8 + r;
  if (n < NA) {
    const int nd = b*NA + n;
    float* myrow = &row[r][0][0];

    // ================= message phase (y stays in registers)
    float rpa[28];
    {
      const float4* bp = (const float4*)(rp + ((size_t)nd*64 + g)*28);
      #pragma unroll
      for (int q = 0; q < 7; ++q) {
        const float4 v = bp[q];
        rpa[q*4+0] = v.x; rpa[q*4+1] = v.y; rpa[q*4+2] = v.z; rpa[q*4+3] = v.w;
      }
    }
    float y0 = 0.0f, y1 = 0.0f, y2 = 0.0f, y3 = 0.0f, y4 = 0.0f;
    if constexpr (!LAST) {
      // x0 has only scalar-regular (embed): sr += rp*w0*s1 ; vr += rp*w1*s1*u
      const float wm0 = wtp[0*FD + g], wm1 = wtp[1*FD + g];
      #pragma unroll
      for (int jr = 0; jr < 28; ++jr) {
        const int j = jr + (jr >= n ? 1 : 0);
        const float t0 = rpa[jr] * x_sh[j][0][g];
        y0 += wm0*t0;
        const float t1 = wm1*t0;
        y1 += t1*us_sh[r][jr][0];
        y2 += t1*us_sh[r][jr][1];
        y3 += t1*us_sh[r][jr][2];
      }
    } else {
      // last-iteration channel mask [1,0,0,0]: only the two parity scalars
      const float wm0 = wtp[0*FD+g], wm3 = wtp[3*FD+g];
      const float wm5 = wtp[10*FD+g], wm8 = wtp[13*FD+g];
      #pragma unroll
      for (int jr = 0; jr < 28; ++jr) {
        const int j = jr + (jr >= n ? 1 : 0);
        const float ux = us_sh[r][jr][0], uy = us_sh[r][jr][1], uz = us_sh[r][jr][2];
        const float s1  = x_sh[j][0][g];
        const float dot1 = x_sh[j][1][g]*ux + x_sh[j][2][g]*uy + x_sh[j][3][g]*uz;
        const float s1p = x_sh[j][4][g];
        const float dotp = x_sh[j][5][g]*ux + x_sh[j][6][g]*uy + x_sh[j][7][g]*uz;
        y0 += rpa[jr]*(wm0*s1  + wm3*dot1);
        y4 += rpa[jr]*(wm5*s1p + wm8*dotp);
      }
    }

    // ================= x1 = x + y
    float x1[8];
    if constexpr (!LAST) {
      x1[0] = x_sh[n][0][g] + y0;
      x1[1] = y1; x1[2] = y2; x1[3] = y3;
      x1[4] = 0.0f; x1[5] = 0.0f; x1[6] = 0.0f; x1[7] = 0.0f;
    } else {
      #pragma unroll
      for (int pc = 0; pc < 8; ++pc) {
        float v = x_sh[n][pc][g];
        if (pc == 0) v += y0;
        if (pc == 4) v += y4;
        x1[pc] = v;
      }
    }
    #pragma unroll
    for (int pc = 0; pc < 8; ++pc) myrow[pc*64 + g] = x1[pc];

    // ================= h = silu(d1(x1)) -> same LDS row (same-wave RAW)
    float hr[8];
    denseRow(myrow, d1w, d1b, g, hr);
    #pragma unroll
    for (int p = 0; p < 2; ++p) {
      const float sv = hr[p*4];
      const float sg = 1.0f / (1.0f + expf(-sv));
      myrow[(p*4+0)*64+g] = sv*sg;
      myrow[(p*4+1)*64+g] = hr[p*4+1]*sg;
      myrow[(p*4+2)*64+g] = hr[p*4+2]*sg;
      myrow[(p*4+3)*64+g] = hr[p*4+3]*sg;
    }

    // ================= x2 = d2(h) + y ; x3 = x2 + tp(x2, xEF, tens_w)
    float h2[8];
    denseRow(myrow, d2w, d2b, g, h2);
    float x2[8], x3[8];
    if constexpr (!LAST) {
      x2[0] = h2[0] + y0; x2[1] = h2[1] + y1; x2[2] = h2[2] + y2; x2[3] = h2[3] + y3;
      x2[4] = h2[4]; x2[5] = h2[5]; x2[6] = h2[6]; x2[7] = h2[7];
    } else {
      #pragma unroll
      for (int pc = 0; pc < 8; ++pc) {
        float v = h2[pc];
        if (pc == 0) v += y0;
        if (pc == 4) v += y4;
        x2[pc] = v;
      }
    }
    {
      const float efx = Ef[b*3+0], efy = Ef[b*3+1], efz = Ef[b*3+2];
      const float bbv[8] = {1.0f, efx, efy, efz, 1.0f, efx, efy, efz};
      float w20[20];
      #pragma unroll
      for (int q = 0; q < 20; ++q) w20[q] = tens_w[q*FD + g];
      float o[8] = {0,0,0,0,0,0,0,0};
      tp20(x2, bbv, w20, o);
      #pragma unroll
      for (int pc = 0; pc < 8; ++pc) {
        x3[pc] = x2[pc] + o[pc];
        myrow[pc*64 + g] = x3[pc];
      }
    }

    // ================= td = dense(x3, tdw) ; x4 = tp(x3, td, td_tp_w)
    float td[8];
    denseRow(myrow, tdw, nullptr, g, td);
    if constexpr (LAST) {
      // only the scalar-regular output feeds the energy:
      // paths (p1,p2)=(0,0): w[0],w[3]; (1,1): w[15],w[18]
      const float wa = td_tp_w[0*FD+g],  wb = td_tp_w[3*FD+g];
      const float wc = td_tp_w[15*FD+g], wd = td_tp_w[18*FD+g];
      const float o0 = wa*(x3[0]*td[0])
                     + wb*(x3[1]*td[1] + x3[2]*td[2] + x3[3]*td[3])
                     + wc*(x3[4]*td[4])
                     + wd*(x3[5]*td[5] + x3[6]*td[6] + x3[7]*td[7]);
      float part = o0 * out_w[g];
      #pragma unroll
      for (int off = 32; off > 0; off >>= 1) part += __shfl_xor(part, off, 64);
      if (g == 0) atomicAdd(&out[b], part + ebias[Z[nd]]);
    } else {
      float w20[20];
      #pragma unroll
      for (int q = 0; q < 20; ++q) w20[q] = td_tp_w[q*FD + g];
      float o[8] = {0,0,0,0,0,0,0,0};
      tp20(x3, td, w20, o);
      #pragma unroll
      for (int pc = 0; pc < 8; ++pc) xout[(size_t)nd*512 + pc*64 + g] = o[pc];
    }
  }
}

// ---------------------------------------------------------------------------
extern "C" void kernel_launch(void* const* d_in, const int* in_sizes, int n_in,
                              void* d_out, int out_size, void* d_ws, size_t ws_size,
                              hipStream_t stream)
{
  (void)in_sizes; (void)n_in; (void)out_size; (void)ws_size;
  const int*   Z     = (const int*)  d_in[0];
  const float* pos   = (const float*)d_in[1];
  const float* Ef    = (const float*)d_in[2];
  // d_in[3]/d_in[4] (dst_idx/src_idx): full i!=j meshgrid, reproduced analytically.
  const float* embed = (const float*)d_in[5];
  const float* mpbw  = (const float*)d_in[6];
  const float* mptpw = (const float*)d_in[7];
  const float* d1w   = (const float*)d_in[8];
  const float* d1b   = (const float*)d_in[9];
  const float* d2w   = (const float*)d_in[10];
  const float* d2b   = (const float*)d_in[11];
  const float* tensw = (const float*)d_in[12];
  const float* tdw   = (const float*)d_in[13];
  const float* tdtpw = (const float*)d_in[14];
  const float* outw  = (const float*)d_in[15];
  const float* ebias = (const float*)d_in[16];
  float* out = (float*)d_out;

  float* logc = (float*)d_ws;                // 64 floats
  float* rpT  = logc + 64;                   // RPLANE floats (reused per iter)
  float* xg   = rpT + RPLANE;                // BN*512 floats

  init_logc_kernel<<<1, 64, 0, stream>>>(logc);
  // it = 0
  edge_rproj_kernel<<<BN, 256, 0, stream>>>(pos, mpbw, logc, rpT, out); // + zero out
  iter_kernel<false><<<NB*4, 512, 0, stream>>>(Z, pos, Ef, embed, mptpw,
      d1w, d1b, d2w, d2b, tensw, tdw, tdtpw, outw, ebias,
      rpT, nullptr, xg, nullptr);
  // it = 1 (rpT reused; stream order guarantees iter0 is done with it)
  edge_rproj_kernel<<<BN, 256, 0, stream>>>(pos, mpbw + 4096, logc, rpT, nullptr);
  iter_kernel<true><<<NB*4, 512, 0, stream>>>(Z, pos, Ef, embed, mptpw + 20*64,
      d1w + 16384, d1b + 128, d2w + 16384, d2b + 128, tensw + 20*64,
      tdw + 16384, tdtpw + 20*64, outw, ebias,
      rpT, xg, nullptr, out);
}

// Round 7
// 515.905 us; speedup vs baseline: 1.2965x; 1.2965x over previous
//
#include <hip/hip_runtime.h>

// Problem constants (from reference setup)
#define NB 128            // batches
#define NA 29             // atoms per batch
#define BN (NB*NA)        // 3712 nodes
#define FD 64             // feature dim
#define RPLANE (BN*64*28) // one iteration's edge projections: 6,651,904 floats

// ws layout (floats): logc[64] | rp[RPLANE] | x[BN*512] | y[BN*512] (~41.8 MB)

// ---------------------------------------------------------------------------
// Kernel 0: 64 binomial log-coefficients (3 lgammaf per edge-thread hoisted).
// ---------------------------------------------------------------------------
__global__ void init_logc_kernel(float* __restrict__ logc)
{
  const int k = threadIdx.x;   // 64 threads
  logc[k] = lgammaf(64.0f) - lgammaf((float)k + 1.0f) - lgammaf(64.0f - (float)k);
}

// ---------------------------------------------------------------------------
// Kernel A: one block per (batch,dst) node; 28 edges; radial basis projected
// through ONE iteration's mp_basis_w slice. Writes rp[(bn*64+g)*28 + jr].
// Also zeroes d_out when outz != null (re-zeroed every call: harness does not
// re-poison between graph replays and iter-1 accumulates via atomicAdd).
// ---------------------------------------------------------------------------
__global__ __launch_bounds__(256, 3) void edge_rproj_kernel(
    const float* __restrict__ pos,      // [BN][3]
    const float* __restrict__ Wb,       // [64][64] (iteration slice)
    const float* __restrict__ logc_tab, // [64]
    float* __restrict__ rp,
    float* __restrict__ outz)
{
  __shared__ float elu[28], el1mu[28], efc[28];
  __shared__ float rads[28][FD];
  const int bn = blockIdx.x, b = bn / NA, n = bn - b*NA;
  const int tid = threadIdx.x, lane = tid & 63, wv = tid >> 6;

  if (outz != nullptr && bn == 0 && tid < NB) outz[tid] = 0.0f;

  if (tid < 28) {
    const int jr = tid, j = jr + (jr >= n ? 1 : 0);
    const float dx = pos[(b*NA+j)*3+0] - pos[(b*NA+n)*3+0];
    const float dy = pos[(b*NA+j)*3+1] - pos[(b*NA+n)*3+1];
    const float dz = pos[(b*NA+j)*3+2] - pos[(b*NA+n)*3+2];
    const float r  = sqrtf(dx*dx + dy*dy + dz*dz + 1e-12f);
    const float u  = 1.0f/(1.0f + r);
    elu[jr]   = logf(u);
    el1mu[jr] = logf(fmaxf(1.0f - u, 1e-12f));
    const float x2 = (r*0.2f)*(r*0.2f);
    efc[jr] = (x2 < 1.0f) ? expf(1.0f - 1.0f/fmaxf(1.0f - x2, 1e-12f)) : 0.0f;
  }
  const float kk   = (float)lane;
  const float logc = logc_tab[lane];
  __syncthreads();                      // elu/el1mu/efc shared across waves

  #pragma unroll
  for (int i = 0; i < 7; ++i) {         // wave-private rows: no barrier below
    const int e = wv*7 + i;
    rads[e][lane] = expf(logc + kk*elu[e] + (63.0f - kk)*el1mu[e]) * efc[e];
  }
  float wb[64];
  #pragma unroll
  for (int k = 0; k < 64; ++k) wb[k] = Wb[k*FD + lane];

  #pragma unroll
  for (int i = 0; i < 7; ++i) {
    const int jr = wv*7 + i;
    float a0 = 0.0f;
    #pragma unroll
    for (int k4 = 0; k4 < 16; ++k4) {
      const float4 rv = *(const float4*)&rads[jr][k4*4];  // same-wave RAW
      a0 += wb[k4*4+0]*rv.x + wb[k4*4+1]*rv.y + wb[k4*4+2]*rv.z + wb[k4*4+3]*rv.w;
    }
    rp[((size_t)bn*64 + lane)*28 + jr] = a0;
  }
}

// ---------------------------------------------------------------------------
// Kernel B: iteration-0 messages. x0 has ONLY scalar-regular = embed[Z]:
// per edge sr += rp*w0*s1 ; vr += rp*w1*s1*u ; pseudo outputs zero.
// ---------------------------------------------------------------------------
__global__ __launch_bounds__(512) void msg0_kernel(
    const int*   __restrict__ Z,
    const float* __restrict__ pos,
    const float* __restrict__ embed,
    const float* __restrict__ wtp,      // mp_tp_w[0] : [20][64]
    const float* __restrict__ rp,
    float* __restrict__ y)              // [BN][8][64]
{
  __shared__ float emb_sh[NA][FD];
  __shared__ float posb[NA][3];
  __shared__ float us_sh[8][28][3];
  const int bi = blockIdx.x, b = bi >> 2, shard = bi & 3;
  const int tid = threadIdx.x, r = tid >> 6, g = tid & 63;

  if (tid < NA) {
    posb[tid][0] = pos[(b*NA+tid)*3+0];
    posb[tid][1] = pos[(b*NA+tid)*3+1];
    posb[tid][2] = pos[(b*NA+tid)*3+2];
  }
  __syncthreads();
  for (int idx = tid; idx < NA*FD; idx += 512)
    emb_sh[idx>>6][idx&63] = embed[Z[b*NA + (idx>>6)]*FD + (idx&63)];
  if (tid < 224) {
    const int rr = tid/28, jr = tid - rr*28, nn = shard*8 + rr;
    if (nn < NA) {
      const int j = jr + (jr >= nn ? 1 : 0);
      const float dx = posb[j][0]-posb[nn][0];
      const float dy = posb[j][1]-posb[nn][1];
      const float dz = posb[j][2]-posb[nn][2];
      const float ri = 1.0f / sqrtf(dx*dx + dy*dy + dz*dz + 1e-12f);
      us_sh[rr][jr][0] = dx*ri; us_sh[rr][jr][1] = dy*ri; us_sh[rr][jr][2] = dz*ri;
    }
  }
  __syncthreads();

  const int n = shard*8 + r;
  if (n >= NA) return;
  const int bn = b*NA + n;
  const float wm0 = wtp[0*FD + g], wm1 = wtp[1*FD + g];

  float rpa[28];
  {
    const float4* bp = (const float4*)(rp + ((size_t)bn*64 + g)*28);
    #pragma unroll
    for (int q = 0; q < 7; ++q) {
      const float4 v = bp[q];
      rpa[q*4+0] = v.x; rpa[q*4+1] = v.y; rpa[q*4+2] = v.z; rpa[q*4+3] = v.w;
    }
  }
  float y0 = 0.0f, y1 = 0.0f, y2 = 0.0f, y3 = 0.0f;
  #pragma unroll
  for (int jr = 0; jr < 28; ++jr) {
    const int j = jr + (jr >= n ? 1 : 0);
    const float t0 = rpa[jr] * emb_sh[j][g];
    y0 += wm0*t0;
    const float t1 = wm1*t0;
    y1 += t1*us_sh[r][jr][0];
    y2 += t1*us_sh[r][jr][1];
    y3 += t1*us_sh[r][jr][2];
  }
  float* yb = y + (size_t)bn*512 + g;
  yb[0] = y0; yb[64] = y1; yb[128] = y2; yb[192] = y3;
  yb[256] = 0.0f; yb[320] = 0.0f; yb[384] = 0.0f; yb[448] = 0.0f;
}

// ---------------------------------------------------------------------------
// Kernel D: iteration-1 messages; last-iteration mask [1,0,0,0] -> y0,y4 only.
// ---------------------------------------------------------------------------
__global__ __launch_bounds__(512) void msg1_kernel(
    const float* __restrict__ pos,
    const float* __restrict__ wtp,      // mp_tp_w[1] : [20][64]
    const float* __restrict__ rp,
    const float* __restrict__ x,        // [BN][8][64]
    float* __restrict__ y)
{
  __shared__ float x_sh[NA][8][FD];     // 59392 B
  __shared__ float posb[NA][3];
  __shared__ float us_sh[8][28][3];
  const int bi = blockIdx.x, b = bi >> 2, shard = bi & 3;
  const int tid = threadIdx.x, r = tid >> 6, g = tid & 63;

  if (tid < NA) {
    posb[tid][0] = pos[(b*NA+tid)*3+0];
    posb[tid][1] = pos[(b*NA+tid)*3+1];
    posb[tid][2] = pos[(b*NA+tid)*3+2];
  }
  __syncthreads();
  {
    float4* dst = (float4*)&x_sh[0][0][0];
    const float4* src = (const float4*)(x + (size_t)b*NA*512);
    for (int i = tid; i < NA*512/4; i += 512) dst[i] = src[i];
  }
  if (tid < 224) {
    const int rr = tid/28, jr = tid - rr*28, nn = shard*8 + rr;
    if (nn < NA) {
      const int j = jr + (jr >= nn ? 1 : 0);
      const float dx = posb[j][0]-posb[nn][0];
      const float dy = posb[j][1]-posb[nn][1];
      const float dz = posb[j][2]-posb[nn][2];
      const float ri = 1.0f / sqrtf(dx*dx + dy*dy + dz*dz + 1e-12f);
      us_sh[rr][jr][0] = dx*ri; us_sh[rr][jr][1] = dy*ri; us_sh[rr][jr][2] = dz*ri;
    }
  }
  __syncthreads();

  const int n = shard*8 + r;
  if (n >= NA) return;
  const int bn = b*NA + n;
  const float wm0 = wtp[0*FD+g], wm3 = wtp[3*FD+g];
  const float wm5 = wtp[10*FD+g], wm8 = wtp[13*FD+g];

  float rpa[28];
  {
    const float4* bp = (const float4*)(rp + ((size_t)bn*64 + g)*28);
    #pragma unroll
    for (int q = 0; q < 7; ++q) {
      const float4 v = bp[q];
      rpa[q*4+0] = v.x; rpa[q*4+1] = v.y; rpa[q*4+2] = v.z; rpa[q*4+3] = v.w;
    }
  }
  float y0 = 0.0f, y4 = 0.0f;
  #pragma unroll
  for (int jr = 0; jr < 28; ++jr) {
    const int j = jr + (jr >= n ? 1 : 0);
    const float ux = us_sh[r][jr][0], uy = us_sh[r][jr][1], uz = us_sh[r][jr][2];
    const float s1  = x_sh[j][0][g];
    const float dot1 = x_sh[j][1][g]*ux + x_sh[j][2][g]*uy + x_sh[j][3][g]*uz;
    const float s1p = x_sh[j][4][g];
    const float dotp = x_sh[j][5][g]*ux + x_sh[j][6][g]*uy + x_sh[j][7][g]*uz;
    y0 += rpa[jr]*(wm0*s1  + wm3*dot1);
    y4 += rpa[jr]*(wm5*s1p + wm8*dotp);
  }
  y[(size_t)bn*512 + g]       = y0;
  y[(size_t)bn*512 + 256 + g] = y4;
}

// ---------------------------------------------------------------------------
// 20-path Clebsch-Gordan tensor product at one feature index.
// ---------------------------------------------------------------------------
__device__ __forceinline__ void tp20(const float* a, const float* bb,
                                     const float* w, float* o)
{
  #pragma unroll
  for (int p1 = 0; p1 < 2; ++p1) {
    #pragma unroll
    for (int p2 = 0; p2 < 2; ++p2) {
      const float* w5 = w + 5*(2*p1 + p2);
      const float s1 = a[p1*4+0], x1 = a[p1*4+1], y1 = a[p1*4+2], z1 = a[p1*4+3];
      const float s2 = bb[p2*4+0], x2 = bb[p2*4+1], y2 = bb[p2*4+2], z2 = bb[p2*4+3];
      const int so = (p1 == p2) ? 0 : 4;   // dest parity for T1..T4
      const int vo = 4 - so;               // dest parity for T5 (cross)
      o[so+0] += w5[0]*(s1*s2) + w5[3]*(x1*x2 + y1*y2 + z1*z2);
      o[so+1] += w5[1]*(s1*x2) + w5[2]*(x1*s2);
      o[so+2] += w5[1]*(s1*y2) + w5[2]*(y1*s2);
      o[so+3] += w5[1]*(s1*z2) + w5[2]*(z1*s2);
      o[vo+1] += w5[4]*(y1*z2 - z1*y2);
      o[vo+2] += w5[4]*(z1*x2 - x1*z2);
      o[vo+3] += w5[4]*(x1*y2 - y1*x2);
    }
  }
}

// ---------------------------------------------------------------------------
// Per-node dense with LDS-STAGED weights (wsrc = 4 mats of [64][64] in LDS).
// Input row in the wave's private LDS row (broadcast float4 reads); weight
// reads: 64 lanes hit consecutive banks -> conflict-free.
// ---------------------------------------------------------------------------
__device__ __forceinline__ void denseRowL(const float* __restrict__ in,
                                          const float* __restrict__ wsrc,
                                          const float* __restrict__ bias,
                                          int g, float o[8])
{
  #pragma unroll
  for (int p = 0; p < 2; ++p) {
    {
      const float* Wp = wsrc + (p*2+0)*4096 + g;
      float acc = bias ? bias[p*64 + g] : 0.0f;
      #pragma unroll
      for (int f4 = 0; f4 < 16; ++f4) {
        const float w0 = Wp[(f4*4+0)*64], w1 = Wp[(f4*4+1)*64];
        const float w2 = Wp[(f4*4+2)*64], w3 = Wp[(f4*4+3)*64];
        const float4 xv = *(const float4*)&in[(p*4+0)*64 + f4*4];
        acc += w0*xv.x + w1*xv.y + w2*xv.z + w3*xv.w;
      }
      o[p*4+0] = acc;
    }
    {
      const float* Wp = wsrc + (p*2+1)*4096 + g;
      float a1 = 0.0f, a2 = 0.0f, a3 = 0.0f;
      #pragma unroll
      for (int f4 = 0; f4 < 16; ++f4) {
        const float w0 = Wp[(f4*4+0)*64], w1 = Wp[(f4*4+1)*64];
        const float w2 = Wp[(f4*4+2)*64], w3 = Wp[(f4*4+3)*64];
        const float4 xa = *(const float4*)&in[(p*4+1)*64 + f4*4];
        const float4 xb = *(const float4*)&in[(p*4+2)*64 + f4*4];
        const float4 xc = *(const float4*)&in[(p*4+3)*64 + f4*4];
        a1 += w0*xa.x + w1*xa.y + w2*xa.z + w3*xa.w;
        a2 += w0*xb.x + w1*xb.y + w2*xb.z + w3*xb.w;
        a3 += w0*xc.x + w1*xc.y + w2*xc.z + w3*xc.w;
      }
      o[p*4+1] = a1; o[p*4+2] = a2; o[p*4+3] = a3;
    }
  }
}

// ---------------------------------------------------------------------------
// Kernel C/E: per-node phases, 8 nodes per 512-thread block (wave r owns node
// blockIdx*8+r; 464*8 = 3712 exactly). Each dense phase stages its 64 KB
// weight set into LDS ONCE PER BLOCK (round-5 streamed 192 KB per WAVE from
// L2 = 712 MB/iter -> the 9%-occupancy latency wall). LDS = 64K + 16K = 80 KB
// -> 2 blocks/CU; (512,2) caps VGPR at 128 (live set ~60 without the msg
// phase; spill tripwire = WRITE_SIZE).
// ---------------------------------------------------------------------------
template<bool LAST>
__global__ __launch_bounds__(512, 2) void node_kernel(
    const int*   __restrict__ Z,
    const float* __restrict__ embed,
    const float* __restrict__ Ef,
    const float* __restrict__ d1w, const float* __restrict__ d1b,
    const float* __restrict__ d2w, const float* __restrict__ d2b,
    const float* __restrict__ tens_w,
    const float* __restrict__ tdw,
    const float* __restrict__ td_tp_w,
    const float* __restrict__ out_w,
    const float* __restrict__ ebias,
    const float* __restrict__ xin,      // LAST only
    const float* __restrict__ yin,
    float* __restrict__ xout,           // !LAST only
    float* __restrict__ out)            // LAST only
{
  __shared__ float wstage[4*64*64];     // 64 KB: one dense's 4 weight mats
  __shared__ float row[8][8][FD];       // 16 KB: wave-private staging rows
  const int tid = threadIdx.x, r = tid >> 6, g = tid & 63;
  const int nd = blockIdx.x*8 + r;
  const int b  = nd / NA;
  float* myrow = &row[r][0][0];

  // ---- stage d1w
  {
    const float4* src = (const float4*)d1w;
    float4* dst = (float4*)wstage;
    #pragma unroll
    for (int i = 0; i < 8; ++i) dst[tid + i*512] = src[tid + i*512];
  }

  // ---- x1 = x + y (y in registers)
  float y0, y1, y2, y3, y4;
  float x1[8];
  if constexpr (!LAST) {
    float yvf[8];
    #pragma unroll
    for (int pc = 0; pc < 8; ++pc) yvf[pc] = yin[(size_t)nd*512 + pc*64 + g];
    x1[0] = embed[Z[nd]*FD + g] + yvf[0];
    #pragma unroll
    for (int pc = 1; pc < 8; ++pc) x1[pc] = yvf[pc];
    y0 = yvf[0]; y1 = yvf[1]; y2 = yvf[2]; y3 = yvf[3]; y4 = 0.0f;
  } else {
    y0 = yin[(size_t)nd*512 + g];
    y4 = yin[(size_t)nd*512 + 256 + g];
    y1 = y2 = y3 = 0.0f;
    #pragma unroll
    for (int pc = 0; pc < 8; ++pc) {
      float v = xin[(size_t)nd*512 + pc*64 + g];
      if (pc == 0) v += y0;
      if (pc == 4) v += y4;
      x1[pc] = v;
    }
  }
  #pragma unroll
  for (int pc = 0; pc < 8; ++pc) myrow[pc*64 + g] = x1[pc];
  __syncthreads();                      // wstage ready (row same-wave RAW)

  // ---- h = silu(d1(x1)) -> same LDS row
  {
    float hr[8];
    denseRowL(myrow, wstage, d1b, g, hr);
    #pragma unroll
    for (int p = 0; p < 2; ++p) {
      const float sv = hr[p*4];
      const float sg = 1.0f / (1.0f + expf(-sv));
      myrow[(p*4+0)*64+g] = sv*sg;
      myrow[(p*4+1)*64+g] = hr[p*4+1]*sg;
      myrow[(p*4+2)*64+g] = hr[p*4+2]*sg;
      myrow[(p*4+3)*64+g] = hr[p*4+3]*sg;
    }
  }
  __syncthreads();                      // all waves done with d1 weights
  {
    const float4* src = (const float4*)d2w;
    float4* dst = (float4*)wstage;
    #pragma unroll
    for (int i = 0; i < 8; ++i) dst[tid + i*512] = src[tid + i*512];
  }
  __syncthreads();                      // d2 weights ready

  // ---- x2 = d2(h) + y ; x3 = x2 + tp(x2, xEF, tens_w)
  float x3[8];
  {
    float h2[8];
    denseRowL(myrow, wstage, d2b, g, h2);
    float x2[8];
    x2[0] = h2[0] + y0; x2[1] = h2[1] + y1; x2[2] = h2[2] + y2; x2[3] = h2[3] + y3;
    x2[4] = h2[4] + y4; x2[5] = h2[5]; x2[6] = h2[6]; x2[7] = h2[7];
    const float efx = Ef[b*3+0], efy = Ef[b*3+1], efz = Ef[b*3+2];
    const float bbv[8] = {1.0f, efx, efy, efz, 1.0f, efx, efy, efz};
    float w20[20];
    #pragma unroll
    for (int q = 0; q < 20; ++q) w20[q] = tens_w[q*FD + g];
    float o[8] = {0,0,0,0,0,0,0,0};
    tp20(x2, bbv, w20, o);
    #pragma unroll
    for (int pc = 0; pc < 8; ++pc) {
      x3[pc] = x2[pc] + o[pc];
      myrow[pc*64 + g] = x3[pc];
    }
  }
  __syncthreads();                      // all waves done with d2 weights
  {
    const float4* src = (const float4*)tdw;
    float4* dst = (float4*)wstage;
    #pragma unroll
    for (int i = 0; i < 8; ++i) dst[tid + i*512] = src[tid + i*512];
  }
  __syncthreads();                      // td weights ready

  // ---- td = dense(x3, tdw) ; x4 = tp(x3, td, td_tp_w)
  {
    float td[8];
    denseRowL(myrow, wstage, nullptr, g, td);
    if constexpr (LAST) {
      // only the scalar-regular output feeds the energy:
      // paths (p1,p2)=(0,0): w[0],w[3]; (1,1): w[15],w[18]
      const float wa = td_tp_w[0*FD+g],  wb = td_tp_w[3*FD+g];
      const float wc = td_tp_w[15*FD+g], wd = td_tp_w[18*FD+g];
      const float o0 = wa*(x3[0]*td[0])
                     + wb*(x3[1]*td[1] + x3[2]*td[2] + x3[3]*td[3])
                     + wc*(x3[4]*td[4])
                     + wd*(x3[5]*td[5] + x3[6]*td[6] + x3[7]*td[7]);
      float part = o0 * out_w[g];
      #pragma unroll
      for (int off = 32; off > 0; off >>= 1) part += __shfl_xor(part, off, 64);
      if (g == 0) atomicAdd(&out[b], part + ebias[Z[nd]]);
    } else {
      float w20[20];
      #pragma unroll
      for (int q = 0; q < 20; ++q) w20[q] = td_tp_w[q*FD + g];
      float o[8] = {0,0,0,0,0,0,0,0};
      tp20(x3, td, w20, o);
      #pragma unroll
      for (int pc = 0; pc < 8; ++pc) xout[(size_t)nd*512 + pc*64 + g] = o[pc];
    }
  }
}

// ---------------------------------------------------------------------------
extern "C" void kernel_launch(void* const* d_in, const int* in_sizes, int n_in,
                              void* d_out, int out_size, void* d_ws, size_t ws_size,
                              hipStream_t stream)
{
  (void)in_sizes; (void)n_in; (void)out_size; (void)ws_size;
  const int*   Z     = (const int*)  d_in[0];
  const float* pos   = (const float*)d_in[1];
  const float* Ef    = (const float*)d_in[2];
  // d_in[3]/d_in[4] (dst_idx/src_idx): full i!=j meshgrid, reproduced analytically.
  const float* embed = (const float*)d_in[5];
  const float* mpbw  = (const float*)d_in[6];
  const float* mptpw = (const float*)d_in[7];
  const float* d1w   = (const float*)d_in[8];
  const float* d1b   = (const float*)d_in[9];
  const float* d2w   = (const float*)d_in[10];
  const float* d2b   = (const float*)d_in[11];
  const float* tensw = (const float*)d_in[12];
  const float* tdw   = (const float*)d_in[13];
  const float* tdtpw = (const float*)d_in[14];
  const float* outw  = (const float*)d_in[15];
  const float* ebias = (const float*)d_in[16];
  float* out = (float*)d_out;

  float* logc = (float*)d_ws;                // 64
  float* rpT  = logc + 64;                   // RPLANE (reused per iter)
  float* xg   = rpT + RPLANE;                // BN*512
  float* yg   = xg + (size_t)BN*512;         // BN*512

  init_logc_kernel<<<1, 64, 0, stream>>>(logc);
  // it = 0
  edge_rproj_kernel<<<BN, 256, 0, stream>>>(pos, mpbw, logc, rpT, out); // + zero out
  msg0_kernel<<<NB*4, 512, 0, stream>>>(Z, pos, embed, mptpw, rpT, yg);
  node_kernel<false><<<BN/8, 512, 0, stream>>>(Z, embed, Ef,
      d1w, d1b, d2w, d2b, tensw, tdw, tdtpw, outw, ebias,
      nullptr, yg, xg, nullptr);
  // it = 1 (rpT reused; stream order guarantees msg0 is done with it)
  edge_rproj_kernel<<<BN, 256, 0, stream>>>(pos, mpbw + 4096, logc, rpT, nullptr);
  msg1_kernel<<<NB*4, 512, 0, stream>>>(pos, mptpw + 20*64, rpT, xg, yg);
  node_kernel<true><<<BN/8, 512, 0, stream>>>(Z, embed, Ef,
      d1w + 16384, d1b + 128, d2w + 16384, d2b + 128, tensw + 20*64,
      tdw + 16384, tdtpw + 20*64, outw, ebias,
      xg, yg, nullptr, out);
}